// Round 11
// baseline (123.697 us; speedup 1.0000x reference)
//
#include <hip/hip_runtime.h>

#define BLOCK 512
typedef float v2f __attribute__((ext_vector_type(2)));
typedef float v4f __attribute__((ext_vector_type(4)));   // clang-native for nontemporal builtin

// ---------- packed fp32 (VOP3P) ----------
__device__ __forceinline__ v2f pk_fma(v2f a, v2f b, v2f c) {
  v2f d;
  asm("v_pk_fma_f32 %0, %1, %2, %3" : "=v"(d) : "v"(a), "v"(b), "v"(c));
  return d;
}
__device__ __forceinline__ v2f pk_mul(v2f a, v2f b) {
  v2f d;
  asm("v_pk_mul_f32 %0, %1, %2" : "=v"(d) : "v"(a), "v"(b));
  return d;
}
// d = (s.lo * p.hi, s.hi * p.lo)  -- component-swapped src1 via op_sel
__device__ __forceinline__ v2f pk_mul_swap(v2f s, v2f p) {
  v2f d;
  asm("v_pk_mul_f32 %0, %1, %2 op_sel:[0,1] op_sel_hi:[1,0]" : "=v"(d) : "v"(s), "v"(p));
  return d;
}

// ---------- cross-lane xor within 16-lane rows (butterfly reduces) ----------
template<int CTRL>
__device__ __forceinline__ float dpp_f(float v) {
  return __int_as_float(__builtin_amdgcn_mov_dpp(__float_as_int(v), CTRL, 0xF, 0xF, true));
}
template<int MASK>
__device__ __forceinline__ float shx(float v) {
  if constexpr (MASK == 1)      return dpp_f<0xB1>(v);   // quad_perm xor1
  else if constexpr (MASK == 2) return dpp_f<0x4E>(v);   // quad_perm xor2
  else if constexpr (MASK == 8) return dpp_f<0x128>(v);  // row_ror:8 == xor8 in row16
  else  // MASK == 4: ds_swizzle BitMode xor=4
    return __int_as_float(__builtin_amdgcn_ds_swizzle(__float_as_int(v), 0x101F));
}

// forward one-layer index map in X basis
__device__ __forceinline__ int gmap(int b) {
#pragma unroll
  for (int j = 0; j < 7; ++j) b ^= ((b >> (j + 1)) & 1) << j;
  b ^= (b & 1) << 7;
  return b;
}

// masks m_q = p^3(e_q): q0..q7 -> 0x32,0x56,0xAC,0x59,0xB3,0x66,0xCC,0x99
#define MQ_PACKED 0x99CC66B359AC5632ULL

// build X-basis product-state pieces for one sample row
__device__ __forceinline__ void build_w(const float* th, int u, v2f* wr2, float* wup) {
  float uf[8], vf[8];
#pragma unroll
  for (int q = 0; q < 8; ++q) {
    const float h = 0.5f * th[q];
    const float c_ = __cosf(h), s_ = __sinf(h);
    uf[q] = c_ + s_; vf[q] = c_ - s_;
  }
  v2f P01; P01.x = uf[0]; P01.y = vf[0];
  const float r12[4] = {uf[1] * uf[2], vf[1] * uf[2], uf[1] * vf[2], vf[1] * vf[2]};
#pragma unroll
  for (int k = 0; k < 8; ++k) {
    const float rest = r12[k & 3] * ((k & 4) ? vf[3] : uf[3]);
    v2f rr; rr.x = rest; rr.y = rest;
    wr2[k] = pk_mul(P01, rr);
  }
  const bool b4 = (u & 1), b5 = (u & 2), b6 = (u & 4), b7 = (u & 8);
  const float f4 = b4 ? vf[4] : uf[4], g4 = b4 ? uf[4] : vf[4];
  const float f5 = b5 ? vf[5] : uf[5], g5 = b5 ? uf[5] : vf[5];
  const float f6 = b6 ? vf[6] : uf[6], g6 = b6 ? uf[6] : vf[6];
  const float f7 = b7 ? vf[7] : uf[7], g7 = b7 ? uf[7] : vf[7];
  const float A0 = f4 * f5, A1 = g4 * f5, A2 = f4 * g5, A3 = g4 * g5;
  const float B0 = f6 * f7, B1 = g6 * f7, B2 = f6 * g7, B3 = g6 * g7;
  const float wu = A0 * B0;
  wup[0] = wu * (A3 * B0);   // mL=3
  wup[1] = wu * (A1 * B1);   // mL=5
  wup[2] = wu * (A2 * B2);   // mL=A
  wup[3] = wup[1];           // mL=5
  wup[4] = wu * (A3 * B2);   // mL=B
  wup[5] = wu * (A2 * B1);   // mL=6
  wup[6] = wu * (A0 * B3);   // mL=C
  wup[7] = wu * (A1 * B2);   // mL=9
}

// ---- Phase C helpers: K read as float4; 4 sample-rows share every K load ----
template<int Q, int XOR, bool SWAP>
__device__ __forceinline__ void dot1r(const float4* kb4, const v2f (&w)[4][8],
                                      const float (&wup)[4][8], float (&zp)[4][8]) {
  v2f a[4];
#pragma unroll
  for (int r = 0; r < 4; ++r) { a[r].x = 0.f; a[r].y = 0.f; }
#pragma unroll
  for (int k2 = 0; k2 < 4; ++k2) {
    const float4 kv = kb4[(Q * 4 + k2) * 16];
    v2f klo; klo.x = kv.x; klo.y = kv.y;
    v2f khi; khi.x = kv.z; khi.y = kv.w;
    const int k0 = 2 * k2, k1 = 2 * k2 + 1;
#pragma unroll
    for (int r = 0; r < 4; ++r) {
      v2f p0 = SWAP ? pk_mul_swap(w[r][k0], w[r][k0 ^ XOR]) : pk_mul(w[r][k0], w[r][k0 ^ XOR]);
      v2f p1 = SWAP ? pk_mul_swap(w[r][k1], w[r][k1 ^ XOR]) : pk_mul(w[r][k1], w[r][k1 ^ XOR]);
      a[r] = pk_fma(p0, klo, a[r]);
      a[r] = pk_fma(p1, khi, a[r]);
    }
  }
#pragma unroll
  for (int r = 0; r < 4; ++r) zp[r][Q] = (a[r].x + a[r].y) * wup[r][Q];
}
template<int Q1, int Q2, int XOR, bool SWAP>
__device__ __forceinline__ void dot2r(const float4* kb4, const v2f (&w)[4][8],
                                      const float (&wup)[4][8], float (&zp)[4][8]) {
  v2f a1[4], a2[4];
#pragma unroll
  for (int r = 0; r < 4; ++r) {
    a1[r].x = a1[r].y = 0.f;
    a2[r].x = a2[r].y = 0.f;
  }
#pragma unroll
  for (int k2 = 0; k2 < 4; ++k2) {
    const float4 kv1 = kb4[(Q1 * 4 + k2) * 16];
    const float4 kv2 = kb4[(Q2 * 4 + k2) * 16];
    v2f k1lo; k1lo.x = kv1.x; k1lo.y = kv1.y;
    v2f k1hi; k1hi.x = kv1.z; k1hi.y = kv1.w;
    v2f k2lo; k2lo.x = kv2.x; k2lo.y = kv2.y;
    v2f k2hi; k2hi.x = kv2.z; k2hi.y = kv2.w;
    const int k0 = 2 * k2, k1 = 2 * k2 + 1;
#pragma unroll
    for (int r = 0; r < 4; ++r) {
      v2f p0 = SWAP ? pk_mul_swap(w[r][k0], w[r][k0 ^ XOR]) : pk_mul(w[r][k0], w[r][k0 ^ XOR]);
      v2f p1 = SWAP ? pk_mul_swap(w[r][k1], w[r][k1 ^ XOR]) : pk_mul(w[r][k1], w[r][k1 ^ XOR]);
      a1[r] = pk_fma(p0, k1lo, a1[r]); a1[r] = pk_fma(p1, k1hi, a1[r]);
      a2[r] = pk_fma(p0, k2lo, a2[r]); a2[r] = pk_fma(p1, k2hi, a2[r]);
    }
  }
#pragma unroll
  for (int r = 0; r < 4; ++r) {
    zp[r][Q1] = (a1[r].x + a1[r].y) * wup[r][Q1];
    zp[r][Q2] = (a2[r].x + a2[r].y) * wup[r][Q2];
  }
}

// (512,2): 256 blocks = 1 block/CU = 8 waves/CU = 2 waves/SIMD; VGPR cap 256.
// Each wave carries 16 samples (4 rows x 4 lane-groups) -> every LDS broadcast
// read (fcw/K/pwt/pb) feeds 4 FMA streams; ILP replaces the lost TLP.
__global__ __launch_bounds__(BLOCK, 2) void qcnn_kernel(
    const float* __restrict__ x,   const float* __restrict__ fcw,
    const float* __restrict__ fcb, const float* __restrict__ qp,
    const float* __restrict__ pw,  const float* __restrict__ pb,
    float* __restrict__ out)
{
  __shared__ float s_fcw[8 * 512];        // [q][e]      16 KB
  __shared__ float s_pwt[8 * 512];        // [q][o] transposed  16 KB
  __shared__ float s_pb[512];             //              2 KB
  __shared__ float s_beta[256];           //              1 KB
  __shared__ float s_K3[8][4][16][4];     // [q][k2][u][j]  8 KB

  const int tid = threadIdx.x;
  const int wave = tid >> 6;
  const int lane = tid & 63;
  const int u = lane & 15;       // circuit bits 4..7
  const int g = lane >> 4;       // sample group within wave

  const int base = blockIdx.x * 128 + wave * 16;

  // ---- x prefetch FIRST: 4 rows x 8 float4 = 32 loads in flight; HBM latency
  //      overlaps the entire prologue (staging + K build + 2 barriers) ----
  float4 xp[4][8];
#pragma unroll
  for (int r = 0; r < 4; ++r) {
    const float* xr = x + (size_t)(base + r * 4 + g) * 512 + u * 4;
#pragma unroll
    for (int t = 0; t < 8; ++t) xp[r][t] = *(const float4*)(xr + t * 64);
  }

  // ---- prologue: all-coalesced global reads ----
  for (int i = tid; i < 1024; i += BLOCK)
    ((float4*)s_fcw)[i] = ((const float4*)fcw)[i];
  // pw natural [512][8] -> transposed s_pwt[q][o]; coalesced float4 read,
  // scalar ds_writes land 2-way per bank (free).
  for (int i = tid; i < 1024; i += BLOCK) {
    const float4 v = ((const float4*)pw)[i];   // row=i>>1, cols 4*(i&1)..+3
    const int row = i >> 1, c0 = 4 * (i & 1);
    s_pwt[(c0 + 0) * 512 + row] = v.x;
    s_pwt[(c0 + 1) * 512 + row] = v.y;
    s_pwt[(c0 + 2) * 512 + row] = v.z;
    s_pwt[(c0 + 3) * 512 + row] = v.w;
  }
  if (tid < 128) ((float4*)s_pb)[tid] = ((const float4*)pb)[tid];
  if (tid < 256) {
    const int c = tid;
    const int i1 = gmap(c);
    const int i2 = gmap(i1);
    float ang = 0.f;
#pragma unroll
    for (int q = 0; q < 8; ++q) {
      ang += (((c  >> q) & 1) ? 0.5f : -0.5f) * qp[q];
      ang += (((i1 >> q) & 1) ? 0.5f : -0.5f) * qp[8 + q];
      ang += (((i2 >> q) & 1) ? 0.5f : -0.5f) * qp[16 + q];
    }
    s_beta[c] = ang;
  }
  __syncthreads();

  // ---- K tables: K_q[c] = cos(beta[c^m_q] - beta[c]) / 256, float4-packed ----
  for (int i = tid; i < 2048; i += BLOCK) {
    const int q = i >> 8, c = i & 255;
    const int m = (int)((MQ_PACKED >> (8 * q)) & 0xFF);
    const float kv = __cosf(s_beta[c ^ m] - s_beta[c]) * (1.0f / 256.0f);
    s_K3[q][(c & 15) >> 2][c >> 4][c & 3] = kv;
  }
  __syncthreads();

  // ---- Phase A: angles; one fcw LDS read feeds 4 rows ----
  v2f acc[4][8];
#pragma unroll
  for (int r = 0; r < 4; ++r)
#pragma unroll
    for (int q = 0; q < 8; ++q) { acc[r][q].x = 0.f; acc[r][q].y = 0.f; }
#pragma unroll
  for (int t = 0; t < 8; ++t) {
    v2f x01[4], x23[4];
#pragma unroll
    for (int r = 0; r < 4; ++r) {
      x01[r].x = xp[r][t].x; x01[r].y = xp[r][t].y;
      x23[r].x = xp[r][t].z; x23[r].y = xp[r][t].w;
    }
#pragma unroll
    for (int q = 0; q < 8; ++q) {
      const float4 wv = *(const float4*)(s_fcw + q * 512 + u * 4 + t * 64);
      v2f w01; w01.x = wv.x; w01.y = wv.y;
      v2f w23; w23.x = wv.z; w23.y = wv.w;
#pragma unroll
      for (int r = 0; r < 4; ++r) {
        acc[r][q] = pk_fma(x01[r], w01, acc[r][q]);
        acc[r][q] = pk_fma(x23[r], w23, acc[r][q]);
      }
    }
  }
  float th[4][8];
#pragma unroll
  for (int q = 0; q < 8; ++q) {
    const float fb = fcb[q];
#pragma unroll
    for (int r = 0; r < 4; ++r) {
      float a_ = acc[r][q].x + acc[r][q].y;
      a_ += shx<1>(a_);
      a_ += shx<2>(a_);
      a_ += shx<4>(a_);
      a_ += shx<8>(a_);
      th[r][q] = a_ + fb;
    }
  }

  // ---- Phase B: X-basis real product-state factors, 4 rows ----
  v2f w4[4][8];
  float wup4[4][8];
#pragma unroll
  for (int r = 0; r < 4; ++r) build_w(th[r], u, w4[r], wup4[r]);

  // ---- Phase C: z_q = sum_c w_c * w_{c^m_q} * K_q[c]; K loads shared by 4 rows ----
  float zp[4][8];
  {
    const float4* kb4 = ((const float4*)s_K3) + u;
    dot1r<0, 1, false>(kb4, w4, wup4, zp);
    dot1r<4, 1, true >(kb4, w4, wup4, zp);
    dot2r<1, 5, 3, false>(kb4, w4, wup4, zp);
    dot2r<2, 6, 6, false>(kb4, w4, wup4, zp);
    dot2r<3, 7, 4, true >(kb4, w4, wup4, zp);
  }
  // sum over the 16 lanes of each sample (result broadcast to all lanes)
#pragma unroll
  for (int q = 0; q < 8; ++q)
#pragma unroll
    for (int r = 0; r < 4; ++r) zp[r][q] += shx<1>(zp[r][q]);
#pragma unroll
  for (int q = 0; q < 8; ++q)
#pragma unroll
    for (int r = 0; r < 4; ++r) zp[r][q] += shx<2>(zp[r][q]);
#pragma unroll
  for (int q = 0; q < 8; ++q)
#pragma unroll
    for (int r = 0; r < 4; ++r) zp[r][q] += shx<4>(zp[r][q]);
#pragma unroll
  for (int q = 0; q < 8; ++q)
#pragma unroll
    for (int r = 0; r < 4; ++r) zp[r][q] += shx<8>(zp[r][q]);

  // ---- Phase E: out = z @ post_w^T + post_b; pwt/pb LDS reads shared by 4 rows.
  //      Non-temporal stores: out is write-once; keep it from evicting x (L3). ----
  v2f zz[4][8];
#pragma unroll
  for (int r = 0; r < 4; ++r)
#pragma unroll
    for (int q = 0; q < 8; ++q) { zz[r][q].x = zp[r][q]; zz[r][q].y = zp[r][q]; }
  float* orp[4];
#pragma unroll
  for (int r = 0; r < 4; ++r) orp[r] = out + (size_t)(base + r * 4 + g) * 512;
#pragma unroll
  for (int tt = 0; tt < 8; ++tt) {
    const int o = u * 4 + tt * 64;
    const float4 pbv = *(const float4*)(s_pb + o);
    v2f r0[4], r1[4];
#pragma unroll
    for (int r = 0; r < 4; ++r) {
      r0[r].x = pbv.x; r0[r].y = pbv.y;
      r1[r].x = pbv.z; r1[r].y = pbv.w;
    }
#pragma unroll
    for (int q = 0; q < 8; ++q) {
      const float4 wv = *(const float4*)(s_pwt + q * 512 + o);
      v2f w01; w01.x = wv.x; w01.y = wv.y;
      v2f w23; w23.x = wv.z; w23.y = wv.w;
#pragma unroll
      for (int r = 0; r < 4; ++r) {
        r0[r] = pk_fma(zz[r][q], w01, r0[r]);
        r1[r] = pk_fma(zz[r][q], w23, r1[r]);
      }
    }
#pragma unroll
    for (int r = 0; r < 4; ++r) {
      v4f ov; ov.x = r0[r].x; ov.y = r0[r].y; ov.z = r1[r].x; ov.w = r1[r].y;
      __builtin_nontemporal_store(ov, (v4f*)(orp[r] + o));
    }
  }
}

extern "C" void kernel_launch(void* const* d_in, const int* in_sizes, int n_in,
                              void* d_out, int out_size, void* d_ws, size_t ws_size,
                              hipStream_t stream) {
  const float* x   = (const float*)d_in[0];
  const float* fcw = (const float*)d_in[1];
  const float* fcb = (const float*)d_in[2];
  const float* qp  = (const float*)d_in[3];
  const float* pw  = (const float*)d_in[4];
  const float* pb  = (const float*)d_in[5];
  float* out = (float*)d_out;

  // 32768 samples / (16 per wave * 8 waves per block) = 256 blocks = 1 block/CU
  dim3 grid(256), block(BLOCK);
  hipLaunchKernelGGL(qcnn_kernel, grid, block, 0, stream, x, fcw, fcb, qp, pw, pb, out);
}